// Round 11
// baseline (391.927 us; speedup 1.0000x reference)
//
#include <hip/hip_runtime.h>
#include <hip/hip_bf16.h>
#include <hip/hip_fp16.h>

#define B_  128
#define S_  512
#define H_  64
#define E_  64
#define G3  192   // 3*H
#define V_  4996
#define VCHUNK 32
#define CHUNK  8             // steps per LDS xw chunk
#define NCHUNK (S_ / CHUNK)  // 64
#define STOK  (S_ + CHUNK)   // scan-ordered tokens + one pad chunk

typedef float f32x4 __attribute__((ext_vector_type(4)));
typedef unsigned int u32;
typedef u32 u32x4 __attribute__((ext_vector_type(4)));
typedef _Float16 f16;
typedef f16 f16x2 __attribute__((ext_vector_type(2)));

__device__ __forceinline__ float fast_rcp(float x) {
#if __has_builtin(__builtin_amdgcn_rcpf)
    return __builtin_amdgcn_rcpf(x);
#else
    return 1.0f / x;
#endif
}
__device__ __forceinline__ float fast_exp(float x) {   // e^x
#if __has_builtin(__builtin_amdgcn_exp2f)
    return __builtin_amdgcn_exp2f(x * 1.44269504f);
#else
    return __expf(x);
#endif
}
__device__ __forceinline__ float sigmoidf_(float x) {
    return fast_rcp(1.0f + fast_exp(-x));
}
__device__ __forceinline__ float tanh_fast(float x) {
    return 1.0f - 2.0f * fast_rcp(1.0f + fast_exp(2.0f * x));
}

// D = a.x*b.x + a.y*b.y + c  (v_dot2_f32_f16)
__device__ __forceinline__ float fdot2_(u32 a, u32 b, float c) {
#if __has_builtin(__builtin_amdgcn_fdot2)
    return __builtin_amdgcn_fdot2(__builtin_bit_cast(f16x2, a),
                                  __builtin_bit_cast(f16x2, b), c, false);
#else
    const f16x2 av = __builtin_bit_cast(f16x2, a);
    const f16x2 bv = __builtin_bit_cast(f16x2, b);
    return fmaf((float)av.x, (float)bv.x, fmaf((float)av.y, (float)bv.y, c));
#endif
}

// ---------------------------------------------------------------------------
// Kernel 1: pre-project the embedding table through the input kernels (fp32).
// ---------------------------------------------------------------------------
__global__ __launch_bounds__(192) void proj_kernel(
    const float* __restrict__ emb,
    const float* __restrict__ Wf, const float* __restrict__ bif,
    const float* __restrict__ Wb, const float* __restrict__ bib,
    float* __restrict__ proj)            // [2][V][192]
{
    const int dir = blockIdx.y;
    const float* W  = dir ? Wb  : Wf;
    const float* bi = dir ? bib : bif;
    const int v0 = blockIdx.x * VCHUNK;
    const int j  = threadIdx.x;
    const int nrows = min(VCHUNK, V_ - v0);

    __shared__ __align__(16) float s_e[VCHUNK * E_];
    for (int i = j; i < nrows * E_; i += 192) s_e[i] = emb[(size_t)v0 * E_ + i];

    float wcol[E_];
    #pragma unroll
    for (int e = 0; e < E_; ++e) wcol[e] = W[e * G3 + j];
    const float bij = bi[j];
    __syncthreads();

    for (int r = 0; r < nrows; ++r) {
        const float4* x4 = (const float4*)(s_e + r * E_);
        float a0 = 0.f, a1 = 0.f, a2 = 0.f, a3 = 0.f;
        #pragma unroll
        for (int e4 = 0; e4 < 16; e4 += 4) {
            float4 h0 = x4[e4], h1 = x4[e4+1], h2 = x4[e4+2], h3 = x4[e4+3];
            a0 = fmaf(h0.x, wcol[4*e4+ 0], a0); a0 = fmaf(h0.y, wcol[4*e4+ 1], a0);
            a0 = fmaf(h0.z, wcol[4*e4+ 2], a0); a0 = fmaf(h0.w, wcol[4*e4+ 3], a0);
            a1 = fmaf(h1.x, wcol[4*e4+ 4], a1); a1 = fmaf(h1.y, wcol[4*e4+ 5], a1);
            a1 = fmaf(h1.z, wcol[4*e4+ 6], a1); a1 = fmaf(h1.w, wcol[4*e4+ 7], a1);
            a2 = fmaf(h2.x, wcol[4*e4+ 8], a2); a2 = fmaf(h2.y, wcol[4*e4+ 9], a2);
            a2 = fmaf(h2.z, wcol[4*e4+10], a2); a2 = fmaf(h2.w, wcol[4*e4+11], a2);
            a3 = fmaf(h3.x, wcol[4*e4+12], a3); a3 = fmaf(h3.y, wcol[4*e4+13], a3);
            a3 = fmaf(h3.z, wcol[4*e4+14], a3); a3 = fmaf(h3.w, wcol[4*e4+15], a3);
        }
        proj[((size_t)dir * V_ + v0 + r) * G3 + j] = ((a0 + a1) + (a2 + a3)) + bij;
    }
}

// Kernel 2: pack recurrent kernels to f16 pairs per gate column.
__global__ void upack_kernel(const float* __restrict__ Uf,
                             const float* __restrict__ Ub,
                             u32* __restrict__ Uh)    // [2][192][32]
{
    const int dir = blockIdx.x;
    const float* U = dir ? Ub : Uf;
    u32* o = Uh + (size_t)dir * G3 * 32;
    for (int k = threadIdx.x; k < G3 * 32; k += blockDim.x) {
        const int j = k >> 5, kk = k & 31;
        f16x2 p;
        p.x = (f16)U[(2 * kk    ) * G3 + j];
        p.y = (f16)U[(2 * kk + 1) * G3 + j];
        o[(size_t)j * 32 + kk] = __builtin_bit_cast(u32, p);
    }
}

// ---------------------------------------------------------------------------
// Kernel 3: the scan. ONE WAVE handles TWO sequences (same direction -> the
// 96 pinned f16 U-column VGPRs are shared). The two independent recurrences
// interleave: seq1's dot issue fills seq0's latency bubbles (LDS RAW,
// fdot2 chains, transcendental chains) and vice versa — attacking the ~650
// stall cyc/step that bounded the single-seq structure (R10: 980 cyc/step at
// 15% VALUBusy, null result vs R9 => stalls were latency, not vmem waits).
// ---------------------------------------------------------------------------
__global__ __launch_bounds__(64)
__attribute__((amdgpu_waves_per_eu(1, 1)))
void gru_scan10(
    const int*   __restrict__ inputs,   // [B,S]
    const float* __restrict__ proj,     // [2][V][192]
    const u32*   __restrict__ Uh,       // [2][192][32] f16-pairs
    const float* __restrict__ brf, const float* __restrict__ brb,
    float* __restrict__ gru_out)        // [B,S,2H]
{
    const int dir  = blockIdx.x & 1;
    const int pair = blockIdx.x >> 1;
    const int b0   = pair * 2, b1 = pair * 2 + 1;
    const int u    = threadIdx.x;          // == unit

    const float* eproj = proj + (size_t)dir * V_ * G3;
    const float* br    = dir ? brb : brf;

    __shared__ __align__(16) int   s_tok[2][STOK];
    __shared__ __align__(16) f16   s_h[2][H_];
    __shared__ __align__(16) float s_xw[2][2][CHUNK * G3];  // [buf][seq] 24 KB

    for (int t = u; t < S_; t += 64) {
        const int tt = dir ? (S_ - 1 - t) : t;
        s_tok[0][t] = inputs[b0 * S_ + tt];
        s_tok[1][t] = inputs[b1 * S_ + tt];
    }
    for (int t = S_ + u; t < STOK; t += 64) { s_tok[0][t] = 0; s_tok[1][t] = 0; }
    s_h[0][u] = (f16)0.0f;
    s_h[1][u] = (f16)0.0f;
    __builtin_amdgcn_wave_barrier();

    // f16-packed U columns: 3 x 8 x u32x4 = 96 VGPRs, pinned, SHARED by both seqs.
    u32x4 wz[8], wr[8], wc[8];
    {
        const u32x4* pz = (const u32x4*)(Uh + ((size_t)dir * G3 + u      ) * 32);
        const u32x4* pr = (const u32x4*)(Uh + ((size_t)dir * G3 + u + 64 ) * 32);
        const u32x4* pc = (const u32x4*)(Uh + ((size_t)dir * G3 + u + 128) * 32);
        #pragma unroll
        for (int k = 0; k < 8; ++k) { wz[k] = pz[k]; wr[k] = pr[k]; wc[k] = pc[k]; }
        #pragma unroll
        for (int k = 0; k < 8; ++k) {
            asm volatile("" : "+v"(wz[k]));
            asm volatile("" : "+v"(wr[k]));
            asm volatile("" : "+v"(wc[k]));
        }
    }
    const float br0 = br[u], br1 = br[u + 64], br2 = br[u + 128];
    float hprev0 = 0.0f, hprev1 = 0.0f;

    // ---- chunk staging: 6 f32x4 per lane per seq (8-step chunk) ----------
    f32x4 ld0[6], ld1[6];
    auto stage_issue = [&](int baseStep) {
        #pragma unroll
        for (int i = 0; i < 6; ++i) {
            const int idx = i * 64 + u;      // 16B slot (0..383)
            const int row = idx / 48;
            const int off = idx - row * 48;
            ld0[i] = *(const f32x4*)(eproj + (size_t)s_tok[0][baseStep + row] * G3 + off * 4);
            ld1[i] = *(const f32x4*)(eproj + (size_t)s_tok[1][baseStep + row] * G3 + off * 4);
        }
    };
    auto stage_write = [&](int nbuf) {
        #pragma unroll
        for (int i = 0; i < 6; ++i) {
            const int idx = i * 64 + u;
            *(f32x4*)(&s_xw[nbuf][0][idx * 4]) = ld0[i];
            *(f32x4*)(&s_xw[nbuf][1][idx * 4]) = ld1[i];
        }
    };

    stage_issue(0);
    stage_write(0);
    __builtin_amdgcn_wave_barrier();

    float* outb0 = gru_out + (size_t)b0 * S_ * (2 * H_) + dir * H_ + u;
    float* outb1 = gru_out + (size_t)b1 * S_ * (2 * H_) + dir * H_ + u;

    for (int c = 0; c < NCHUNK; ++c) {
        const int buf = c & 1;
        stage_issue((c + 1) * CHUNK);         // next chunk, pad-safe

        #pragma unroll 1
        for (int t0 = 0; t0 < CHUNK; ++t0) {
            const int t = c * CHUNK + t0;

            const int tok0 = s_tok[0][t];
            const int tok1 = s_tok[1][t];
            const float x00 = s_xw[buf][0][t0 * G3 + u];
            const float x01 = s_xw[buf][0][t0 * G3 + u + 64];
            const float x02 = s_xw[buf][0][t0 * G3 + u + 128];
            const float x10 = s_xw[buf][1][t0 * G3 + u];
            const float x11 = s_xw[buf][1][t0 * G3 + u + 64];
            const float x12 = s_xw[buf][1][t0 * G3 + u + 128];

            // read both h rows up front (16 broadcast b128)
            const u32x4* h0p = (const u32x4*)s_h[0];
            const u32x4* h1p = (const u32x4*)s_h[1];
            u32x4 h0v[8], h1v[8];
            #pragma unroll
            for (int k = 0; k < 8; ++k) h0v[k] = h0p[k];
            #pragma unroll
            for (int k = 0; k < 8; ++k) h1v[k] = h1p[k];

            // dots: 2 seqs x 3 gates x 4 indep chains (192 fdot2)
            float a0z[4] = {0,0,0,0}, a0r[4] = {0,0,0,0}, a0c[4] = {0,0,0,0};
            float a1z[4] = {0,0,0,0}, a1r[4] = {0,0,0,0}, a1c[4] = {0,0,0,0};
            #pragma unroll
            for (int k = 0; k < 8; ++k) {
                const u32x4 v0 = h0v[k], v1 = h1v[k];
                const u32x4 vz = wz[k], vr = wr[k], vc = wc[k];
                a0z[0] = fdot2_(v0.x, vz.x, a0z[0]);
                a0z[1] = fdot2_(v0.y, vz.y, a0z[1]);
                a0z[2] = fdot2_(v0.z, vz.z, a0z[2]);
                a0z[3] = fdot2_(v0.w, vz.w, a0z[3]);
                a1z[0] = fdot2_(v1.x, vz.x, a1z[0]);
                a1z[1] = fdot2_(v1.y, vz.y, a1z[1]);
                a1z[2] = fdot2_(v1.z, vz.z, a1z[2]);
                a1z[3] = fdot2_(v1.w, vz.w, a1z[3]);
                a0r[0] = fdot2_(v0.x, vr.x, a0r[0]);
                a0r[1] = fdot2_(v0.y, vr.y, a0r[1]);
                a0r[2] = fdot2_(v0.z, vr.z, a0r[2]);
                a0r[3] = fdot2_(v0.w, vr.w, a0r[3]);
                a1r[0] = fdot2_(v1.x, vr.x, a1r[0]);
                a1r[1] = fdot2_(v1.y, vr.y, a1r[1]);
                a1r[2] = fdot2_(v1.z, vr.z, a1r[2]);
                a1r[3] = fdot2_(v1.w, vr.w, a1r[3]);
                a0c[0] = fdot2_(v0.x, vc.x, a0c[0]);
                a0c[1] = fdot2_(v0.y, vc.y, a0c[1]);
                a0c[2] = fdot2_(v0.z, vc.z, a0c[2]);
                a0c[3] = fdot2_(v0.w, vc.w, a0c[3]);
                a1c[0] = fdot2_(v1.x, vc.x, a1c[0]);
                a1c[1] = fdot2_(v1.y, vc.y, a1c[1]);
                a1c[2] = fdot2_(v1.z, vc.z, a1c[2]);
                a1c[3] = fdot2_(v1.w, vc.w, a1c[3]);
            }
            const float d00 = ((a0z[0]+a0z[1]) + (a0z[2]+a0z[3])) + br0;
            const float d01 = ((a0r[0]+a0r[1]) + (a0r[2]+a0r[3])) + br1;
            const float d02 = ((a0c[0]+a0c[1]) + (a0c[2]+a0c[3])) + br2;
            const float d10 = ((a1z[0]+a1z[1]) + (a1z[2]+a1z[3])) + br0;
            const float d11 = ((a1r[0]+a1r[1]) + (a1r[2]+a1r[3])) + br1;
            const float d12 = ((a1c[0]+a1c[1]) + (a1c[2]+a1c[3])) + br2;

            // gates, two independent chains
            const float z0 = sigmoidf_(x00 + d00);
            const float z1 = sigmoidf_(x10 + d10);
            const float r0 = sigmoidf_(x01 + d01);
            const float r1 = sigmoidf_(x11 + d11);
            const float hh0 = tanh_fast(fmaf(r0, d02, x02));
            const float hh1 = tanh_fast(fmaf(r1, d12, x12));
            const float hn0 = fmaf(z0, hprev0 - hh0, hh0);
            const float hn1 = fmaf(z1, hprev1 - hh1, hh1);
            const float res0 = (tok0 != 0) ? hn0 : hprev0;
            const float res1 = (tok1 != 0) ? hn1 : hprev1;
            hprev0 = res0;
            hprev1 = res1;

            s_h[0][u] = (f16)res0;
            s_h[1][u] = (f16)res1;
            __builtin_amdgcn_wave_barrier();   // writes before next reads

            const int tt = dir ? (S_ - 1 - t) : t;
            outb0[(size_t)tt * (2 * H_)] = res0;  // coalesced, never waited
            outb1[(size_t)tt * (2 * H_)] = res1;
        }

        stage_write(buf ^ 1);   // vm wait once per 8 steps
        __builtin_amdgcn_wave_barrier();
    }
}

// x1 = sigmoid(gru_out @ w1 + b1), x2 = sigmoid(gru_out @ w2 + b2)
__global__ __launch_bounds__(256) void head_kernel(
    const float* __restrict__ gru,      // [B*S, 2H]
    const float* __restrict__ w1, const float* __restrict__ b1,
    const float* __restrict__ w2, const float* __restrict__ b2,
    float* __restrict__ x1, float* __restrict__ x2)
{
    __shared__ __align__(16) float s_w1[2 * H_];
    __shared__ __align__(16) float s_w2[2 * H_];
    const int tid = threadIdx.x;
    if (tid < 2 * H_)      s_w1[tid]          = w1[tid];
    else                   s_w2[tid - 2 * H_] = w2[tid - 2 * H_];
    __syncthreads();

    const int i = blockIdx.x * 256 + tid;
    const float4* g4 = (const float4*)(gru + (size_t)i * (2 * H_));
    float a1 = b1[0], a2 = b2[0];
    #pragma unroll
    for (int k = 0; k < (2 * H_) / 4; ++k) {
        const float4 v  = g4[k];
        const float4 q1 = ((const float4*)s_w1)[k];
        const float4 q2 = ((const float4*)s_w2)[k];
        a1 += v.x * q1.x + v.y * q1.y + v.z * q1.z + v.w * q1.w;
        a2 += v.x * q2.x + v.y * q2.y + v.z * q2.z + v.w * q2.w;
    }
    x1[i] = 1.0f / (1.0f + __expf(-a1));
    x2[i] = 1.0f / (1.0f + __expf(-a2));
}

extern "C" void kernel_launch(void* const* d_in, const int* in_sizes, int n_in,
                              void* d_out, int out_size, void* d_ws, size_t ws_size,
                              hipStream_t stream) {
    (void)in_sizes; (void)n_in; (void)ws_size; (void)out_size;

    const int*   inputs = (const int*)  d_in[0];
    const float* emb    = (const float*)d_in[1];
    const float* Wf     = (const float*)d_in[2];
    const float* Uf     = (const float*)d_in[3];
    const float* bif    = (const float*)d_in[4];
    const float* brf    = (const float*)d_in[5];
    const float* Wb     = (const float*)d_in[6];
    const float* Ub     = (const float*)d_in[7];
    const float* bib    = (const float*)d_in[8];
    const float* brb    = (const float*)d_in[9];
    const float* w1     = (const float*)d_in[10];
    const float* b1     = (const float*)d_in[11];
    const float* w2     = (const float*)d_in[12];
    const float* b2     = (const float*)d_in[13];

    float* out = (float*)d_out;
    float* x1  = out;                       // [B*S]
    float* x2  = out + (size_t)B_ * S_;     // [B*S]
    float* gru = out + (size_t)2 * B_ * S_; // [B*S, 2H]

    float* proj = (float*)d_ws;
    u32*   Uh   = (u32*)(proj + (size_t)2 * V_ * G3);

    proj_kernel<<<dim3((V_ + VCHUNK - 1) / VCHUNK, 2), 192, 0, stream>>>(
        emb, Wf, bif, Wb, bib, proj);
    upack_kernel<<<2, 256, 0, stream>>>(Uf, Ub, Uh);

    // 64 pairs x 2 directions; each wave runs two sequences.
    gru_scan10<<<B_, 64, 0, stream>>>(inputs, proj, Uh, brf, brb, gru);

    head_kernel<<<(B_ * S_) / 256, 256, 0, stream>>>(gru, w1, b1, w2, b2, x1, x2);
}

// Round 12
// 309.086 us; speedup vs baseline: 1.2680x; 1.2680x over previous
//
#include <hip/hip_runtime.h>
#include <hip/hip_bf16.h>
#include <hip/hip_fp16.h>

#define B_  128
#define S_  512
#define H_  64
#define E_  64
#define G3  192   // 3*H
#define V_  4996
#define VCHUNK 32
#define NSEQ 16              // sequences per block (MFMA M dim)
#define CH   8               // steps per output flush

typedef float f32x4 __attribute__((ext_vector_type(4)));
typedef unsigned int u32;
typedef u32 u32x2 __attribute__((ext_vector_type(2)));
typedef unsigned short u16;
typedef _Float16 f16;
typedef f16 f16x8 __attribute__((ext_vector_type(8)));

__device__ __forceinline__ float fast_rcp(float x) {
#if __has_builtin(__builtin_amdgcn_rcpf)
    return __builtin_amdgcn_rcpf(x);
#else
    return 1.0f / x;
#endif
}
__device__ __forceinline__ float fast_exp(float x) {   // e^x
#if __has_builtin(__builtin_amdgcn_exp2f)
    return __builtin_amdgcn_exp2f(x * 1.44269504f);
#else
    return __expf(x);
#endif
}
__device__ __forceinline__ float sigmoidf_(float x) {
    return fast_rcp(1.0f + fast_exp(-x));
}
__device__ __forceinline__ float tanh_fast(float x) {
    return 1.0f - 2.0f * fast_rcp(1.0f + fast_exp(2.0f * x));
}

// ---------------------------------------------------------------------------
// Kernel 1: pre-project the embedding table through the input kernels (fp32).
//   proj[dir][v][j] = sum_e emb[v][e] * W_dir[e][j] + bi_dir[j]
// ---------------------------------------------------------------------------
__global__ __launch_bounds__(192) void proj_kernel(
    const float* __restrict__ emb,
    const float* __restrict__ Wf, const float* __restrict__ bif,
    const float* __restrict__ Wb, const float* __restrict__ bib,
    float* __restrict__ proj)            // [2][V][192]
{
    const int dir = blockIdx.y;
    const float* W  = dir ? Wb  : Wf;
    const float* bi = dir ? bib : bif;
    const int v0 = blockIdx.x * VCHUNK;
    const int j  = threadIdx.x;
    const int nrows = min(VCHUNK, V_ - v0);

    __shared__ __align__(16) float s_e[VCHUNK * E_];
    for (int i = j; i < nrows * E_; i += 192) s_e[i] = emb[(size_t)v0 * E_ + i];

    float wcol[E_];
    #pragma unroll
    for (int e = 0; e < E_; ++e) wcol[e] = W[e * G3 + j];
    const float bij = bi[j];
    __syncthreads();

    for (int r = 0; r < nrows; ++r) {
        const float4* x4 = (const float4*)(s_e + r * E_);
        float a0 = 0.f, a1 = 0.f, a2 = 0.f, a3 = 0.f;
        #pragma unroll
        for (int e4 = 0; e4 < 16; e4 += 4) {
            float4 h0 = x4[e4], h1 = x4[e4+1], h2 = x4[e4+2], h3 = x4[e4+3];
            a0 = fmaf(h0.x, wcol[4*e4+ 0], a0); a0 = fmaf(h0.y, wcol[4*e4+ 1], a0);
            a0 = fmaf(h0.z, wcol[4*e4+ 2], a0); a0 = fmaf(h0.w, wcol[4*e4+ 3], a0);
            a1 = fmaf(h1.x, wcol[4*e4+ 4], a1); a1 = fmaf(h1.y, wcol[4*e4+ 5], a1);
            a1 = fmaf(h1.z, wcol[4*e4+ 6], a1); a1 = fmaf(h1.w, wcol[4*e4+ 7], a1);
            a2 = fmaf(h2.x, wcol[4*e4+ 8], a2); a2 = fmaf(h2.y, wcol[4*e4+ 9], a2);
            a2 = fmaf(h2.z, wcol[4*e4+10], a2); a2 = fmaf(h2.w, wcol[4*e4+11], a2);
            a3 = fmaf(h3.x, wcol[4*e4+12], a3); a3 = fmaf(h3.y, wcol[4*e4+13], a3);
            a3 = fmaf(h3.z, wcol[4*e4+14], a3); a3 = fmaf(h3.w, wcol[4*e4+15], a3);
        }
        proj[((size_t)dir * V_ + v0 + r) * G3 + j] = ((a0 + a1) + (a2 + a3)) + bij;
    }
}

// ---------------------------------------------------------------------------
// Kernel 2: pack U into per-lane MFMA B-fragments (f16).
// B for mfma_f32_16x16x32_f16: lane l holds col = l&15 (+tile*16),
// k = (l>>4)*8 + j, j=0..7.  Upk[((dir*12 + tile)*2 + kt)*64 + lane].
// ---------------------------------------------------------------------------
__global__ void upackB_kernel(const float* __restrict__ Uf,
                              const float* __restrict__ Ub,
                              f16x8* __restrict__ Upk)
{
    const int gid = blockIdx.x * blockDim.x + threadIdx.x;
    if (gid >= 2 * 12 * 2 * 64) return;
    const int lane = gid & 63;
    const int kt   = (gid >> 6) & 1;
    const int tile = (gid >> 7) % 12;
    const int dir  = (gid >> 7) / 12;
    const float* U = dir ? Ub : Uf;
    const int col = tile * 16 + (lane & 15);
    f16x8 v;
    #pragma unroll
    for (int j = 0; j < 8; ++j) {
        const int k = kt * 32 + (lane >> 4) * 8 + j;
        v[j] = (f16)U[k * G3 + col];
    }
    Upk[gid] = v;
}

// ---------------------------------------------------------------------------
// Kernel 3: MFMA-batched scan. Block = (dir, group of 16 batch rows).
// 4 waves; wave w owns N-tiles {w, w+4, w+8} (cols 16w..16w+16 of z, r, c).
// Per step: A = h'[16x64] f16 from LDS (2 ds_read_b128/lane), 6 MFMA/wave,
// gates lane-local (C row=seq, col=unit), h' written back to the other LDS
// buffer. ONE raw s_barrier per step with explicit lgkmcnt(0) — xw prefetch
// global loads stay in flight across it (no vmcnt drain). Outputs buffered
// in LDS, flushed every 8 steps in a separate loop (no conditional vmem in
// the steady state).
// ---------------------------------------------------------------------------
__global__ __launch_bounds__(256) void gru_mfma(
    const int*   __restrict__ inputs,   // [B,S]
    const float* __restrict__ proj,     // [2][V][192]
    const f16x8* __restrict__ Upk,      // packed B fragments
    const float* __restrict__ brf, const float* __restrict__ brb,
    float* __restrict__ gru_out)        // [B,S,2H]
{
    const int dir   = blockIdx.x & 1;
    const int grp   = blockIdx.x >> 1;      // 0..7
    const int bbase = grp * NSEQ;
    const int tid   = threadIdx.x;
    const int w     = tid >> 6;             // wave 0..3
    const int l     = tid & 63;
    const int q     = l >> 4;               // 0..3
    const int m     = l & 15;
    const int u     = w * 16 + m;           // unit column 0..63

    const float* eproj = proj + (size_t)dir * V_ * G3;
    const float* br    = dir ? brb : brf;

    __shared__ u16 s_tok[S_][NSEQ];                        // 16 KB, scan order
    __shared__ __align__(16) f16   s_h[2][NSEQ][72];       // 4.5 KB, padded
    __shared__ __align__(16) float s_hist[CH][NSEQ][68];   // 34 KB, padded

    for (int i = tid; i < S_ * NSEQ; i += 256) {
        const int t = i >> 4, s = i & 15;
        const int tt = dir ? (S_ - 1 - t) : t;
        s_tok[t][s] = (u16)inputs[(bbase + s) * S_ + tt];
    }
    for (int i = tid; i < 2 * NSEQ * 72; i += 256) ((f16*)s_h)[i] = (f16)0;
    __syncthreads();

    // B fragments for this wave's three tiles (z: w, r: w+4, c: w+8), pinned.
    f16x8 Bz0, Bz1, Br0, Br1, Bc0, Bc1;
    {
        const f16x8* base = Upk + (size_t)dir * 12 * 2 * 64;
        Bz0 = base[((w    ) * 2 + 0) * 64 + l];
        Bz1 = base[((w    ) * 2 + 1) * 64 + l];
        Br0 = base[((w + 4) * 2 + 0) * 64 + l];
        Br1 = base[((w + 4) * 2 + 1) * 64 + l];
        Bc0 = base[((w + 8) * 2 + 0) * 64 + l];
        Bc1 = base[((w + 8) * 2 + 1) * 64 + l];
        asm volatile("" : "+v"(Bz0), "+v"(Bz1), "+v"(Br0),
                          "+v"(Br1), "+v"(Bc0), "+v"(Bc1));
    }
    const float brz = br[u], brr = br[64 + u], brc = br[128 + u];
    float hp0 = 0.f, hp1 = 0.f, hp2 = 0.f, hp3 = 0.f;

    // token regs (4 seqs 4q..4q+3 as u16x4 in a u32x2): cur step & next step
    u32x2 tc = *(const u32x2*)&s_tok[0][4 * q];
    u32x2 tn = *(const u32x2*)&s_tok[1][4 * q];

    // xw prefetch registers: [phase][j*3+g], phase = t&1
    float xw[2][12];
    auto ldxw = [&](int ph, u32x2 tk) {
        #pragma unroll
        for (int j = 0; j < 4; ++j) {
            const int tkj = (tk[j >> 1] >> (16 * (j & 1))) & 0xFFFF;
            const float* rp = eproj + (size_t)tkj * G3;
            xw[ph][j * 3 + 0] = rp[u];
            xw[ph][j * 3 + 1] = rp[64 + u];
            xw[ph][j * 3 + 2] = rp[128 + u];
        }
    };
    ldxw(0, tc);   // xw for t=0

    for (int c = 0; c < S_ / CH; ++c) {
        #pragma unroll
        for (int t0 = 0; t0 < CH; ++t0) {
            const int t   = c * CH + t0;
            const int ph  = t0 & 1;          // == t&1 (CH even)
            const int cur = ph;              // h buffer read this step

            ldxw(ph ^ 1, tn);                // prefetch xw for t+1

            const int t2 = (t + 2 < S_) ? (t + 2) : (S_ - 1);
            const u32x2 ta = *(const u32x2*)&s_tok[t2][4 * q];

            // A fragments: lane l = row m (seq), k = q*8.. (+kt*32)
            const f16x8 a0 = *(const f16x8*)&s_h[cur][m][q * 8];
            const f16x8 a1 = *(const f16x8*)&s_h[cur][m][32 + q * 8];
            asm volatile("s_waitcnt lgkmcnt(0)" ::: "memory");
            __builtin_amdgcn_sched_barrier(0);

            const f32x4 zero = {0.f, 0.f, 0.f, 0.f};
            f32x4 cz = __builtin_amdgcn_mfma_f32_16x16x32_f16(a0, Bz0, zero, 0, 0, 0);
            cz       = __builtin_amdgcn_mfma_f32_16x16x32_f16(a1, Bz1, cz,   0, 0, 0);
            f32x4 cr = __builtin_amdgcn_mfma_f32_16x16x32_f16(a0, Br0, zero, 0, 0, 0);
            cr       = __builtin_amdgcn_mfma_f32_16x16x32_f16(a1, Br1, cr,   0, 0, 0);
            f32x4 cc = __builtin_amdgcn_mfma_f32_16x16x32_f16(a0, Bc0, zero, 0, 0, 0);
            cc       = __builtin_amdgcn_mfma_f32_16x16x32_f16(a1, Bc1, cc,   0, 0, 0);

            // gates: lane-local triples for seqs 4q+j, unit u
            #define STEPJ(j, hpj) {                                              \
                const int tokj = (tc[(j) >> 1] >> (16 * ((j) & 1))) & 0xFFFF;    \
                const float z  = sigmoidf_(xw[ph][(j)*3 + 0] + brz + cz[(j)]);   \
                const float r  = sigmoidf_(xw[ph][(j)*3 + 1] + brr + cr[(j)]);   \
                const float hh = tanh_fast(fmaf(r, cc[(j)] + brc,                \
                                                xw[ph][(j)*3 + 2]));             \
                const float hn = fmaf(z, hpj - hh, hh);                          \
                const float res = (tokj != 0) ? hn : hpj;                        \
                hpj = res;                                                       \
                s_h[cur ^ 1][4 * q + (j)][u] = (f16)res;                         \
                s_hist[t0][4 * q + (j)][u]   = res;                              \
            }
            STEPJ(0, hp0) STEPJ(1, hp1) STEPJ(2, hp2) STEPJ(3, hp3)
            #undef STEPJ

            asm volatile("s_waitcnt lgkmcnt(0)" ::: "memory");  // drain writes
            __builtin_amdgcn_s_barrier();                        // NO vm drain

            tc = tn;
            tn = ta;
        }

        // flush CH steps of outputs (cross-wave reads, after the barrier)
        #pragma unroll
        for (int qq = 0; qq < 8; ++qq) {
            const int idx = qq * 256 + tid;        // 0..2047 f32x4 chunks
            const int st  = idx >> 8;
            const int rem = idx & 255;
            const int sq  = rem >> 4;
            const int uc  = rem & 15;
            const f32x4 v = *(const f32x4*)&s_hist[st][sq][uc * 4];
            const int tg  = c * CH + st;
            const int tt  = dir ? (S_ - 1 - tg) : tg;
            *(f32x4*)(gru_out + ((size_t)(bbase + sq) * S_ + tt) * (2 * H_)
                      + dir * H_ + uc * 4) = v;
        }
        asm volatile("s_waitcnt lgkmcnt(0)" ::: "memory");
        __builtin_amdgcn_s_barrier();   // s_hist safe to overwrite next chunk
    }
}

// x1 = sigmoid(gru_out @ w1 + b1), x2 = sigmoid(gru_out @ w2 + b2)
__global__ __launch_bounds__(256) void head_kernel(
    const float* __restrict__ gru,      // [B*S, 2H]
    const float* __restrict__ w1, const float* __restrict__ b1,
    const float* __restrict__ w2, const float* __restrict__ b2,
    float* __restrict__ x1, float* __restrict__ x2)
{
    __shared__ __align__(16) float s_w1[2 * H_];
    __shared__ __align__(16) float s_w2[2 * H_];
    const int tid = threadIdx.x;
    if (tid < 2 * H_)      s_w1[tid]          = w1[tid];
    else                   s_w2[tid - 2 * H_] = w2[tid - 2 * H_];
    __syncthreads();

    const int i = blockIdx.x * 256 + tid;
    const float4* g4 = (const float4*)(gru + (size_t)i * (2 * H_));
    float a1 = b1[0], a2 = b2[0];
    #pragma unroll
    for (int k = 0; k < (2 * H_) / 4; ++k) {
        const float4 v  = g4[k];
        const float4 q1 = ((const float4*)s_w1)[k];
        const float4 q2 = ((const float4*)s_w2)[k];
        a1 += v.x * q1.x + v.y * q1.y + v.z * q1.z + v.w * q1.w;
        a2 += v.x * q2.x + v.y * q2.y + v.z * q2.z + v.w * q2.w;
    }
    x1[i] = 1.0f / (1.0f + __expf(-a1));
    x2[i] = 1.0f / (1.0f + __expf(-a2));
}

extern "C" void kernel_launch(void* const* d_in, const int* in_sizes, int n_in,
                              void* d_out, int out_size, void* d_ws, size_t ws_size,
                              hipStream_t stream) {
    (void)in_sizes; (void)n_in; (void)ws_size; (void)out_size;

    const int*   inputs = (const int*)  d_in[0];
    const float* emb    = (const float*)d_in[1];
    const float* Wf     = (const float*)d_in[2];
    const float* Uf     = (const float*)d_in[3];
    const float* bif    = (const float*)d_in[4];
    const float* brf    = (const float*)d_in[5];
    const float* Wb     = (const float*)d_in[6];
    const float* Ub     = (const float*)d_in[7];
    const float* bib    = (const float*)d_in[8];
    const float* brb    = (const float*)d_in[9];
    const float* w1     = (const float*)d_in[10];
    const float* b1     = (const float*)d_in[11];
    const float* w2     = (const float*)d_in[12];
    const float* b2     = (const float*)d_in[13];

    float* out = (float*)d_out;
    float* x1  = out;                       // [B*S]
    float* x2  = out + (size_t)B_ * S_;     // [B*S]
    float* gru = out + (size_t)2 * B_ * S_; // [B*S, 2H]

    // workspace: proj [2][V][192] f32 (7.67 MB), then Upk (48 KB)
    float* proj = (float*)d_ws;
    f16x8* Upk  = (f16x8*)(proj + (size_t)2 * V_ * G3);

    proj_kernel<<<dim3((V_ + VCHUNK - 1) / VCHUNK, 2), 192, 0, stream>>>(
        emb, Wf, bif, Wb, bib, proj);
    upackB_kernel<<<12, 256, 0, stream>>>(Uf, Ub, Upk);

    // 2 dirs x 8 groups of 16 sequences; 4 waves per block.
    gru_mfma<<<16, 256, 0, stream>>>(inputs, proj, Upk, brf, brb, gru);

    head_kernel<<<(B_ * S_) / 256, 256, 0, stream>>>(gru, w1, b1, w2, b2, x1, x2);
}

// Round 13
// 260.113 us; speedup vs baseline: 1.5068x; 1.1883x over previous
//
#include <hip/hip_runtime.h>
#include <hip/hip_bf16.h>
#include <hip/hip_fp16.h>

#define B_  128
#define S_  512
#define H_  64
#define E_  64
#define G3  192   // 3*H
#define V_  4996
#define VCHUNK 32
#define CHUNK  8             // steps per LDS xw chunk
#define NCHUNK (S_ / CHUNK)  // 64
#define STOK  (S_ + CHUNK)   // scan-ordered tokens + one pad chunk

typedef float f32x4 __attribute__((ext_vector_type(4)));
typedef unsigned int u32;
typedef u32 u32x4 __attribute__((ext_vector_type(4)));
typedef _Float16 f16;
typedef f16 f16x2 __attribute__((ext_vector_type(2)));

__device__ __forceinline__ float fast_rcp(float x) {
#if __has_builtin(__builtin_amdgcn_rcpf)
    return __builtin_amdgcn_rcpf(x);
#else
    return 1.0f / x;
#endif
}
__device__ __forceinline__ float fast_exp(float x) {   // e^x
#if __has_builtin(__builtin_amdgcn_exp2f)
    return __builtin_amdgcn_exp2f(x * 1.44269504f);
#else
    return __expf(x);
#endif
}
__device__ __forceinline__ float sigmoidf_(float x) {
    return fast_rcp(1.0f + fast_exp(-x));
}
__device__ __forceinline__ float tanh_fast(float x) {
    return 1.0f - 2.0f * fast_rcp(1.0f + fast_exp(2.0f * x));
}

// D = a.x*b.x + a.y*b.y + c  (v_dot2_f32_f16; one operand may be scalar)
__device__ __forceinline__ float fdot2_(u32 a, u32 b, float c) {
#if __has_builtin(__builtin_amdgcn_fdot2)
    return __builtin_amdgcn_fdot2(__builtin_bit_cast(f16x2, a),
                                  __builtin_bit_cast(f16x2, b), c, false);
#else
    const f16x2 av = __builtin_bit_cast(f16x2, a);
    const f16x2 bv = __builtin_bit_cast(f16x2, b);
    return fmaf((float)av.x, (float)bv.x, fmaf((float)av.y, (float)bv.y, c));
#endif
}

// pack two f32 into f16x2 (round toward zero)
__device__ __forceinline__ u32 pack_pk(float a, float b) {
#if __has_builtin(__builtin_amdgcn_cvt_pkrtz)
    return __builtin_bit_cast(u32, __builtin_amdgcn_cvt_pkrtz(a, b));
#else
    f16x2 p; p.x = (f16)a; p.y = (f16)b;
    return __builtin_bit_cast(u32, p);
#endif
}

// ---------------------------------------------------------------------------
// Kernel 1: pre-project the embedding table through the input kernels (fp32).
// ---------------------------------------------------------------------------
__global__ __launch_bounds__(192) void proj_kernel(
    const float* __restrict__ emb,
    const float* __restrict__ Wf, const float* __restrict__ bif,
    const float* __restrict__ Wb, const float* __restrict__ bib,
    float* __restrict__ proj)            // [2][V][192]
{
    const int dir = blockIdx.y;
    const float* W  = dir ? Wb  : Wf;
    const float* bi = dir ? bib : bif;
    const int v0 = blockIdx.x * VCHUNK;
    const int j  = threadIdx.x;
    const int nrows = min(VCHUNK, V_ - v0);

    __shared__ __align__(16) float s_e[VCHUNK * E_];
    for (int i = j; i < nrows * E_; i += 192) s_e[i] = emb[(size_t)v0 * E_ + i];

    float wcol[E_];
    #pragma unroll
    for (int e = 0; e < E_; ++e) wcol[e] = W[e * G3 + j];
    const float bij = bi[j];
    __syncthreads();

    for (int r = 0; r < nrows; ++r) {
        const float4* x4 = (const float4*)(s_e + r * E_);
        float a0 = 0.f, a1 = 0.f, a2 = 0.f, a3 = 0.f;
        #pragma unroll
        for (int e4 = 0; e4 < 16; e4 += 4) {
            float4 h0 = x4[e4], h1 = x4[e4+1], h2 = x4[e4+2], h3 = x4[e4+3];
            a0 = fmaf(h0.x, wcol[4*e4+ 0], a0); a0 = fmaf(h0.y, wcol[4*e4+ 1], a0);
            a0 = fmaf(h0.z, wcol[4*e4+ 2], a0); a0 = fmaf(h0.w, wcol[4*e4+ 3], a0);
            a1 = fmaf(h1.x, wcol[4*e4+ 4], a1); a1 = fmaf(h1.y, wcol[4*e4+ 5], a1);
            a1 = fmaf(h1.z, wcol[4*e4+ 6], a1); a1 = fmaf(h1.w, wcol[4*e4+ 7], a1);
            a2 = fmaf(h2.x, wcol[4*e4+ 8], a2); a2 = fmaf(h2.y, wcol[4*e4+ 9], a2);
            a2 = fmaf(h2.z, wcol[4*e4+10], a2); a2 = fmaf(h2.w, wcol[4*e4+11], a2);
            a3 = fmaf(h3.x, wcol[4*e4+12], a3); a3 = fmaf(h3.y, wcol[4*e4+13], a3);
            a3 = fmaf(h3.z, wcol[4*e4+14], a3); a3 = fmaf(h3.w, wcol[4*e4+15], a3);
        }
        proj[((size_t)dir * V_ + v0 + r) * G3 + j] = ((a0 + a1) + (a2 + a3)) + bij;
    }
}

// Kernel 2: pack recurrent kernels to f16 pairs per gate column.
//   Uh[dir][j][kk] = pack_f16(U[2kk][j], U[2kk+1][j])   kk in [0,32)
__global__ void upack_kernel(const float* __restrict__ Uf,
                             const float* __restrict__ Ub,
                             u32* __restrict__ Uh)    // [2][192][32]
{
    const int dir = blockIdx.x;
    const float* U = dir ? Ub : Uf;
    u32* o = Uh + (size_t)dir * G3 * 32;
    for (int k = threadIdx.x; k < G3 * 32; k += blockDim.x) {
        const int j = k >> 5, kk = k & 31;
        f16x2 p;
        p.x = (f16)U[(2 * kk    ) * G3 + j];
        p.y = (f16)U[(2 * kk + 1) * G3 + j];
        o[(size_t)j * 32 + kk] = __builtin_bit_cast(u32, p);
    }
}

// ---------------------------------------------------------------------------
// Kernel 3: the scan. ONE WAVE per (batch row, direction). Lane u owns unit
// u; gate columns (u, u+64, u+128) in-lane via fdot2 against f16 U columns in
// 96 pinned VGPRs. h is broadcast through SGPRs, NOT LDS: after the update,
// one DPP quad_perm + v_cvt_pkrtz packs (h_even,h_odd) pairs in even lanes,
// then 32 v_readlane lift them to SGPRs consumed directly as the scalar
// operand of v_dot2_f32_f16. This removes the ~120-220 cyc LDS h round-trip
// that headed every step (R9-R12: ~980 cyc/step floor) plus all h DS traffic.
// xw comes from an 8-step LDS chunk (reg-staged, vm wait once per chunk).
// ---------------------------------------------------------------------------
__global__ __launch_bounds__(64)
__attribute__((amdgpu_waves_per_eu(1, 1)))
void gru_scan11(
    const int*   __restrict__ inputs,   // [B,S]
    const float* __restrict__ proj,     // [2][V][192]
    const u32*   __restrict__ Uh,       // [2][192][32] f16-pairs
    const float* __restrict__ brf, const float* __restrict__ brb,
    float* __restrict__ gru_out)        // [B,S,2H]
{
    const int b   = blockIdx.x >> 1;
    const int dir = blockIdx.x & 1;
    const int u   = threadIdx.x;           // == unit

    const float* eproj = proj + (size_t)dir * V_ * G3;
    const float* br    = dir ? brb : brf;

    __shared__ __align__(16) int   s_tok[STOK];          // scan order + pad
    __shared__ __align__(16) float s_xw[2][CHUNK * G3];  // 2 x 6 KB

    for (int t = u; t < S_; t += 64)
        s_tok[t] = inputs[b * S_ + (dir ? (S_ - 1 - t) : t)];
    for (int t = S_ + u; t < STOK; t += 64) s_tok[t] = 0;  // pad -> row 0
    __builtin_amdgcn_wave_barrier();

    // f16-packed U columns: 3 x 8 x u32x4 = 96 VGPRs, pinned.
    u32x4 wz[8], wr[8], wc[8];
    {
        const u32x4* pz = (const u32x4*)(Uh + ((size_t)dir * G3 + u      ) * 32);
        const u32x4* pr = (const u32x4*)(Uh + ((size_t)dir * G3 + u + 64 ) * 32);
        const u32x4* pc = (const u32x4*)(Uh + ((size_t)dir * G3 + u + 128) * 32);
        #pragma unroll
        for (int k = 0; k < 8; ++k) { wz[k] = pz[k]; wr[k] = pr[k]; wc[k] = pc[k]; }
        #pragma unroll
        for (int k = 0; k < 8; ++k) {
            asm volatile("" : "+v"(wz[k]));
            asm volatile("" : "+v"(wr[k]));
            asm volatile("" : "+v"(wc[k]));
        }
    }
    const float br0 = br[u], br1 = br[u + 64], br2 = br[u + 128];
    float res = 0.0f;                      // lane u's h value

    // ---- chunk staging: 6 f32x4 per lane = one 8-step chunk ----------
    f32x4 ld[6];
    auto stage_issue = [&](int baseStep) {
        #pragma unroll
        for (int i = 0; i < 6; ++i) {
            const int idx = i * 64 + u;      // 16B slot (0..383)
            const int row = idx / 48;        // 48 slots per 192-float row
            const int off = idx - row * 48;
            const int tk  = s_tok[baseStep + row];
            ld[i] = *(const f32x4*)(eproj + (size_t)tk * G3 + off * 4);
        }
    };
    auto stage_write = [&](int nbuf) {
        #pragma unroll
        for (int i = 0; i < 6; ++i) {
            const int idx = i * 64 + u;
            *(f32x4*)(&s_xw[nbuf][idx * 4]) = ld[i];
        }
    };

    stage_issue(0);
    stage_write(0);
    __builtin_amdgcn_wave_barrier();

    float* outb = gru_out + (size_t)b * S_ * (2 * H_) + dir * H_ + u;

    for (int c = 0; c < NCHUNK; ++c) {
        const int buf = c & 1;
        stage_issue((c + 1) * CHUNK);        // next chunk loads (pad-safe)

        #pragma unroll 1
        for (int t0 = 0; t0 < CHUNK; ++t0) {
            const int t = c * CHUNK + t0;

            // ---- broadcast h (res) to all lanes via SGPRs ----
            int ri = __builtin_bit_cast(int, res);
            int rn;
#if __has_builtin(__builtin_amdgcn_mov_dpp)
            rn = __builtin_amdgcn_mov_dpp(ri, 0xB1, 0xF, 0xF, true); // quad_perm [1,0,3,2]
#else
            rn = __shfl_xor(ri, 1, 64);
#endif
            const u32 pku = pack_pk(res, __builtin_bit_cast(float, rn));
            u32 hp[32];
            #pragma unroll
            for (int k = 0; k < 32; ++k)
                hp[k] = (u32)__builtin_amdgcn_readlane((int)pku, 2 * k);

            const int   tok = s_tok[t];                       // broadcast b32
            const float x0  = s_xw[buf][t0 * G3 + u];
            const float x1  = s_xw[buf][t0 * G3 + u + 64];
            const float x2  = s_xw[buf][t0 * G3 + u + 128];

            // rec = h . U[:,col]; scalar h pairs x VGPR weight pairs
            float az[4] = {0,0,0,0}, ar_[4] = {0,0,0,0}, ac_[4] = {0,0,0,0};
            #pragma unroll
            for (int k = 0; k < 8; ++k) {
                const u32x4 vz = wz[k], vr = wr[k], vc = wc[k];
                az[0]  = fdot2_(hp[4*k+0], vz.x, az[0]);
                az[1]  = fdot2_(hp[4*k+1], vz.y, az[1]);
                az[2]  = fdot2_(hp[4*k+2], vz.z, az[2]);
                az[3]  = fdot2_(hp[4*k+3], vz.w, az[3]);
                ar_[0] = fdot2_(hp[4*k+0], vr.x, ar_[0]);
                ar_[1] = fdot2_(hp[4*k+1], vr.y, ar_[1]);
                ar_[2] = fdot2_(hp[4*k+2], vr.z, ar_[2]);
                ar_[3] = fdot2_(hp[4*k+3], vr.w, ar_[3]);
                ac_[0] = fdot2_(hp[4*k+0], vc.x, ac_[0]);
                ac_[1] = fdot2_(hp[4*k+1], vc.y, ac_[1]);
                ac_[2] = fdot2_(hp[4*k+2], vc.z, ac_[2]);
                ac_[3] = fdot2_(hp[4*k+3], vc.w, ac_[3]);
            }
            const float d0 = ((az[0]  + az[1])  + (az[2]  + az[3]))  + br0;
            const float d1 = ((ar_[0] + ar_[1]) + (ar_[2] + ar_[3])) + br1;
            const float d2 = ((ac_[0] + ac_[1]) + (ac_[2] + ac_[3])) + br2;

            const float z    = sigmoidf_(x0 + d0);
            const float r    = sigmoidf_(x1 + d1);
            const float hh   = tanh_fast(fmaf(r, d2, x2));
            const float hn   = fmaf(z, res - hh, hh);
            res = (tok != 0) ? hn : res;               // mask_zero carry

            const int tt = dir ? (S_ - 1 - t) : t;
            outb[(size_t)tt * (2 * H_)] = res;         // coalesced, no wait
        }

        stage_write(buf ^ 1);   // vm wait once per 8 steps
        __builtin_amdgcn_wave_barrier();
    }
}

// x1 = sigmoid(gru_out @ w1 + b1), x2 = sigmoid(gru_out @ w2 + b2)
__global__ __launch_bounds__(256) void head_kernel(
    const float* __restrict__ gru,      // [B*S, 2H]
    const float* __restrict__ w1, const float* __restrict__ b1,
    const float* __restrict__ w2, const float* __restrict__ b2,
    float* __restrict__ x1, float* __restrict__ x2)
{
    __shared__ __align__(16) float s_w1[2 * H_];
    __shared__ __align__(16) float s_w2[2 * H_];
    const int tid = threadIdx.x;
    if (tid < 2 * H_)      s_w1[tid]          = w1[tid];
    else                   s_w2[tid - 2 * H_] = w2[tid - 2 * H_];
    __syncthreads();

    const int i = blockIdx.x * 256 + tid;
    const float4* g4 = (const float4*)(gru + (size_t)i * (2 * H_));
    float a1 = b1[0], a2 = b2[0];
    #pragma unroll
    for (int k = 0; k < (2 * H_) / 4; ++k) {
        const float4 v  = g4[k];
        const float4 q1 = ((const float4*)s_w1)[k];
        const float4 q2 = ((const float4*)s_w2)[k];
        a1 += v.x * q1.x + v.y * q1.y + v.z * q1.z + v.w * q1.w;
        a2 += v.x * q2.x + v.y * q2.y + v.z * q2.z + v.w * q2.w;
    }
    x1[i] = 1.0f / (1.0f + __expf(-a1));
    x2[i] = 1.0f / (1.0f + __expf(-a2));
}

extern "C" void kernel_launch(void* const* d_in, const int* in_sizes, int n_in,
                              void* d_out, int out_size, void* d_ws, size_t ws_size,
                              hipStream_t stream) {
    (void)in_sizes; (void)n_in; (void)ws_size; (void)out_size;

    const int*   inputs = (const int*)  d_in[0];
    const float* emb    = (const float*)d_in[1];
    const float* Wf     = (const float*)d_in[2];
    const float* Uf     = (const float*)d_in[3];
    const float* bif    = (const float*)d_in[4];
    const float* brf    = (const float*)d_in[5];
    const float* Wb     = (const float*)d_in[6];
    const float* Ub     = (const float*)d_in[7];
    const float* bib    = (const float*)d_in[8];
    const float* brb    = (const float*)d_in[9];
    const float* w1     = (const float*)d_in[10];
    const float* b1     = (const float*)d_in[11];
    const float* w2     = (const float*)d_in[12];
    const float* b2     = (const float*)d_in[13];

    float* out = (float*)d_out;
    float* x1  = out;                       // [B*S]
    float* x2  = out + (size_t)B_ * S_;     // [B*S]
    float* gru = out + (size_t)2 * B_ * S_; // [B*S, 2H]

    // workspace: proj [2][V][192] f32 (7.67 MB), then Uh [2][192][32] u32 (48 KB)
    float* proj = (float*)d_ws;
    u32*   Uh   = (u32*)(proj + (size_t)2 * V_ * G3);

    proj_kernel<<<dim3((V_ + VCHUNK - 1) / VCHUNK, 2), 192, 0, stream>>>(
        emb, Wf, bif, Wb, bib, proj);
    upack_kernel<<<2, 256, 0, stream>>>(Uf, Ub, Uh);

    gru_scan11<<<B_ * 2, 64, 0, stream>>>(inputs, proj, Uh, brf, brb, gru);

    head_kernel<<<(B_ * S_) / 256, 256, 0, stream>>>(gru, w1, b1, w2, b2, x1, x2);
}